// Round 1
// 624.219 us; speedup vs baseline: 1.0461x; 1.0461x over previous
//
#include <hip/hip_runtime.h>
#include <stdint.h>

typedef __bf16 bf16;
typedef __bf16 bf16x8 __attribute__((ext_vector_type(8)));
typedef __bf16 bf16x4v __attribute__((ext_vector_type(4)));
typedef float f32x4 __attribute__((ext_vector_type(4)));

#define L_SEQ 2048
#define H_DIM 2048
#define KV_DIM 512
#define QKV_LD 3072
#define INTER_DIM 8192

__device__ __forceinline__ void load_lds16(const void* g, void* l) {
  __builtin_amdgcn_global_load_lds(
      (const __attribute__((address_space(1))) void*)g,
      (__attribute__((address_space(3))) void*)l, 16, 0, 0);
}

// ---------------- fused fp32 -> bf16 convert of all 7 weights -------------
__global__ __launch_bounds__(256)
void cvt_all(const float* __restrict__ q, const float* __restrict__ k,
             const float* __restrict__ v, const float* __restrict__ o,
             const float* __restrict__ g, const float* __restrict__ u,
             const float* __restrict__ dn, bf16* __restrict__ WB) {
  const int b = blockIdx.x;
  const float* s;
  size_t doff;
  int lb;
  if (b < 2048)       { s = q;  doff = 0;        lb = b; }
  else if (b < 2560)  { s = k;  doff = 4194304;  lb = b - 2048; }
  else if (b < 3072)  { s = v;  doff = 5242880;  lb = b - 2560; }
  else if (b < 5120)  { s = o;  doff = 6291456;  lb = b - 3072; }
  else if (b < 13312) { s = g;  doff = 10485760; lb = b - 5120; }
  else if (b < 21504) { s = u;  doff = 27262976; lb = b - 13312; }
  else                { s = dn; doff = 44040192; lb = b - 21504; }
  const size_t i = (size_t)lb * 2048 + threadIdx.x * 8;
  float4 a = *(const float4*)(s + i);
  float4 c = *(const float4*)(s + i + 4);
  bf16x8 ov;
  ov[0] = (bf16)a.x; ov[1] = (bf16)a.y; ov[2] = (bf16)a.z; ov[3] = (bf16)a.w;
  ov[4] = (bf16)c.x; ov[5] = (bf16)c.y; ov[6] = (bf16)c.z; ov[7] = (bf16)c.w;
  *(bf16x8*)(WB + doff + i) = ov;
}

// ---------------- RMSNorm: fp32 in -> bf16 out ----------------
__global__ __launch_bounds__(256)
void rmsnorm_bf16(const float* __restrict__ x, const float* __restrict__ w,
                  bf16* __restrict__ out) {
  const int row = blockIdx.x;
  const int t = threadIdx.x;
  const float* xr = x + (size_t)row * H_DIM + t * 8;
  float4 a = *(const float4*)xr;
  float4 b = *(const float4*)(xr + 4);
  float ss = a.x * a.x + a.y * a.y + a.z * a.z + a.w * a.w +
             b.x * b.x + b.y * b.y + b.z * b.z + b.w * b.w;
#pragma unroll
  for (int off = 1; off < 64; off <<= 1) ss += __shfl_xor(ss, off, 64);
  __shared__ float red[4];
  if ((t & 63) == 0) red[t >> 6] = ss;
  __syncthreads();
  ss = red[0] + red[1] + red[2] + red[3];
  const float rs = rsqrtf(ss * (1.0f / H_DIM) + 1e-6f);
  float4 w1 = *(const float4*)(w + t * 8);
  float4 w2 = *(const float4*)(w + t * 8 + 4);
  bf16x8 o;
  o[0] = (bf16)(a.x * rs * w1.x);
  o[1] = (bf16)(a.y * rs * w1.y);
  o[2] = (bf16)(a.z * rs * w1.z);
  o[3] = (bf16)(a.w * rs * w1.w);
  o[4] = (bf16)(b.x * rs * w2.x);
  o[5] = (bf16)(b.y * rs * w2.y);
  o[6] = (bf16)(b.z * rs * w2.z);
  o[7] = (bf16)(b.w * rs * w2.w);
  *(bf16x8*)(out + (size_t)row * H_DIM + t * 8) = o;
}

// -------- fused: hidden = p0+p1+res ; normed = rmsnorm(hidden) --------
__global__ __launch_bounds__(256)
void add_rmsnorm(const float* __restrict__ p0, const float* __restrict__ p1,
                 const float* __restrict__ res, const float* __restrict__ w,
                 float* __restrict__ hidden, bf16* __restrict__ normed) {
  const int row = blockIdx.x;
  const int t = threadIdx.x;
  const size_t base = (size_t)row * H_DIM + t * 8;
  float4 a0 = *(const float4*)(p0 + base);
  float4 a1 = *(const float4*)(p0 + base + 4);
  float4 b0 = *(const float4*)(p1 + base);
  float4 b1 = *(const float4*)(p1 + base + 4);
  float4 c0 = *(const float4*)(res + base);
  float4 c1 = *(const float4*)(res + base + 4);
  float4 h0, h1;
  h0.x = a0.x + b0.x + c0.x; h0.y = a0.y + b0.y + c0.y;
  h0.z = a0.z + b0.z + c0.z; h0.w = a0.w + b0.w + c0.w;
  h1.x = a1.x + b1.x + c1.x; h1.y = a1.y + b1.y + c1.y;
  h1.z = a1.z + b1.z + c1.z; h1.w = a1.w + b1.w + c1.w;
  *(float4*)(hidden + base) = h0;
  *(float4*)(hidden + base + 4) = h1;
  float ss = h0.x * h0.x + h0.y * h0.y + h0.z * h0.z + h0.w * h0.w +
             h1.x * h1.x + h1.y * h1.y + h1.z * h1.z + h1.w * h1.w;
#pragma unroll
  for (int off = 1; off < 64; off <<= 1) ss += __shfl_xor(ss, off, 64);
  __shared__ float red[4];
  if ((t & 63) == 0) red[t >> 6] = ss;
  __syncthreads();
  ss = red[0] + red[1] + red[2] + red[3];
  const float rs = rsqrtf(ss * (1.0f / H_DIM) + 1e-6f);
  float4 w1 = *(const float4*)(w + t * 8);
  float4 w2 = *(const float4*)(w + t * 8 + 4);
  bf16x8 o;
  o[0] = (bf16)(h0.x * rs * w1.x);
  o[1] = (bf16)(h0.y * rs * w1.y);
  o[2] = (bf16)(h0.z * rs * w1.z);
  o[3] = (bf16)(h0.w * rs * w1.w);
  o[4] = (bf16)(h1.x * rs * w2.x);
  o[5] = (bf16)(h1.y * rs * w2.y);
  o[6] = (bf16)(h1.z * rs * w2.z);
  o[7] = (bf16)(h1.w * rs * w2.w);
  *(bf16x8*)(normed + (size_t)row * H_DIM + t * 8) = o;
}

// ---------------- out = p0+p1+p2+p3 + res (float4) ----------------
__global__ __launch_bounds__(256)
void reduce_add4(const float* __restrict__ p, size_t zs,
                 const float* __restrict__ res, float* __restrict__ out) {
  const size_t i = ((size_t)blockIdx.x * 256 + threadIdx.x) * 4;
  float4 a = *(const float4*)(p + i);
  float4 b = *(const float4*)(p + zs + i);
  float4 c = *(const float4*)(p + 2 * zs + i);
  float4 d = *(const float4*)(p + 3 * zs + i);
  float4 r = *(const float4*)(res + i);
  float4 o;
  o.x = a.x + b.x + c.x + d.x + r.x;
  o.y = a.y + b.y + c.y + d.y + r.y;
  o.z = a.z + b.z + c.z + d.z + r.z;
  o.w = a.w + b.w + c.w + d.w + r.w;
  *(float4*)(out + i) = o;
}

// ------- qkv combine: sum 2 fp32 partials -> bf16 qkv + fp32 K/V out ------
__global__ __launch_bounds__(256)
void qkv_combine(const float* __restrict__ p, size_t zs,
                 bf16* __restrict__ qkv, float* __restrict__ outk,
                 float* __restrict__ outv) {
  const size_t i = ((size_t)blockIdx.x * 256 + threadIdx.x) * 4;
  float4 a = *(const float4*)(p + i);
  float4 b = *(const float4*)(p + zs + i);
  float4 s;
  s.x = a.x + b.x; s.y = a.y + b.y; s.z = a.z + b.z; s.w = a.w + b.w;
  bf16x4v o;
  o[0] = (bf16)s.x; o[1] = (bf16)s.y; o[2] = (bf16)s.z; o[3] = (bf16)s.w;
  *(bf16x4v*)(qkv + i) = o;
  const int col = (int)(i % QKV_LD);
  const size_t row = i / QKV_LD;
  if (col >= 2560)      *(float4*)(outv + row * KV_DIM + (col - 2560)) = s;
  else if (col >= 2048) *(float4*)(outk + row * KV_DIM + (col - 2048)) = s;
}

// ======================= 8-phase 256-class GEMM engine =====================
// Tile: 256(M) x 256 or 128(N), BK=32 per K-tile; 512 thr = 8 waves (2Mx4N),
// per-wave 128x64 output (acc = 8x4 f32x4 = 128 VGPR).
// LDS: triple-buffered A/B K-tiles (3 x (16KB+16KB) = 96 KiB).
// Schedule (T3+T4): stage tile tt+2 while computing tt; per K-tile two
// phases {ds_read frags | 2x global_load_lds -> s_barrier -> lgkmcnt(0) ->
// setprio(1) 16 MFMA setprio(0) -> s_barrier}; boundary wait = vmcnt(4):
// next-next tile's 4 loads stay in flight across every barrier (never 0).
// T2 swizzle: 16B slot within each 64B LDS row XORed with (row&3); the
// global SOURCE is inverse-swizzled (rule #21), reads apply the same XOR.

__device__ __forceinline__ void stage_round(const bf16* __restrict__ P,
                                            int ld, int grow0, int k0,
                                            char* ldsdst, int t) {
  const int flat = t * 16;                    // 0..8191 (512 thr x 16B)
  const int row = flat >> 6;                  // 0..127 local row
  const int w = flat & 63;
  const int kk = (w ^ ((row & 3) << 4)) >> 1; // inverse-swizzled k element
  load_lds16(P + (size_t)(grow0 + row) * ld + k0 + kk, ldsdst + flat);
}

__device__ __forceinline__ bf16x8 frag_ld(const bf16* __restrict__ sl,
                                          int row, int l4) {
  // swizzled read: element offset = row*32 + ((l4 ^ (row&3)) * 8)
  return *(const bf16x8*)(sl + row * 32 + ((l4 ^ (row & 3)) << 3));
}

#define PHASE_SYNC_PRE()                                  \
  __builtin_amdgcn_sched_barrier(0);                      \
  __builtin_amdgcn_s_barrier();                           \
  asm volatile("s_waitcnt lgkmcnt(0)" ::: "memory");      \
  __builtin_amdgcn_sched_barrier(0);                      \
  __builtin_amdgcn_s_setprio(1)

#define PHASE_SYNC_POST()                                 \
  __builtin_amdgcn_s_setprio(0);                          \
  __builtin_amdgcn_sched_barrier(0)

// ---- split-K B^T GEMM: C[M,N] += A[M,K] @ B[N,K]^T, fp32 partials ----
__global__ __launch_bounds__(512, 2)
void gemm8_bt(const bf16* __restrict__ A, int lda,
              const bf16* __restrict__ B, int ldb, int kpb,
              float* __restrict__ outf, int ldof, size_t zstride) {
  __shared__ __align__(16) char smem[98304];
  bf16* sA = (bf16*)smem;                 // 3 x 8192 elems (16 KB each)
  bf16* sB = (bf16*)(smem + 49152);
  const int t = threadIdx.x;
  const int lane = t & 63;
  const int l15 = lane & 15, l4 = lane >> 4;
  const int wid = t >> 6;
  const int wr = wid >> 2, wc = wid & 3;

  // XCD-bijective swizzle over the xy grid (nwg % 8 == 0 for all callers)
  const int nwg = gridDim.x * gridDim.y;
  const int bid = blockIdx.y * gridDim.x + blockIdx.x;
  const int swz = (bid & 7) * (nwg >> 3) + (bid >> 3);
  const int m0 = (swz / gridDim.x) * 256;
  const int n0 = (swz % gridDim.x) * 256;
  const int kbeg = blockIdx.z * kpb;
  const int NT = kpb >> 5;

  const f32x4 zero = {0.f, 0.f, 0.f, 0.f};
  f32x4 acc[8][4];
#pragma unroll
  for (int m = 0; m < 8; ++m)
#pragma unroll
    for (int n = 0; n < 4; ++n) acc[m][n] = zero;

  // prologue: stage tiles 0,1; wait tile0 (4 loads in flight afterward)
  stage_round(A, lda, m0, kbeg, (char*)sA, t);
  stage_round(A, lda, m0 + 128, kbeg, (char*)sA + 8192, t);
  stage_round(B, ldb, n0, kbeg, (char*)sB, t);
  stage_round(B, ldb, n0 + 128, kbeg, (char*)sB + 8192, t);
  stage_round(A, lda, m0, kbeg + 32, (char*)sA + 16384, t);
  stage_round(A, lda, m0 + 128, kbeg + 32, (char*)sA + 16384 + 8192, t);
  stage_round(B, ldb, n0, kbeg + 32, (char*)sB + 16384, t);
  stage_round(B, ldb, n0 + 128, kbeg + 32, (char*)sB + 16384 + 8192, t);
  asm volatile("s_waitcnt vmcnt(4)" ::: "memory");
  __builtin_amdgcn_s_barrier();

  int cur = 0, s2 = 2;
  for (int tt = 0; tt < NT; ++tt) {
    const bf16* sAc = sA + cur * 8192;
    const bf16* sBc = sB + cur * 8192;
    const int k2 = kbeg + (tt + 2) * 32;
    bf16x8 af[4], bfr[4];
    // ---------- phase 0: B frags + A m0..3; stage A of tile tt+2 ----------
#pragma unroll
    for (int n = 0; n < 4; ++n)
      bfr[n] = frag_ld(sBc, wc * 64 + n * 16 + l15, l4);
#pragma unroll
    for (int m = 0; m < 4; ++m)
      af[m] = frag_ld(sAc, wr * 128 + m * 16 + l15, l4);
    if (tt + 2 < NT) {
      char* d = (char*)(sA + s2 * 8192);
      stage_round(A, lda, m0, k2, d, t);
      stage_round(A, lda, m0 + 128, k2, d + 8192, t);
    }
    PHASE_SYNC_PRE();
#pragma unroll
    for (int m = 0; m < 4; ++m)
#pragma unroll
      for (int n = 0; n < 4; ++n)
        acc[m][n] = __builtin_amdgcn_mfma_f32_16x16x32_bf16(
            af[m], bfr[n], acc[m][n], 0, 0, 0);
    PHASE_SYNC_POST();
    __builtin_amdgcn_s_barrier();
    // ---------- phase 1: A m4..7 (reuse B frags); stage B of tt+2 ----------
#pragma unroll
    for (int m = 0; m < 4; ++m)
      af[m] = frag_ld(sAc, wr * 128 + 64 + m * 16 + l15, l4);
    if (tt + 2 < NT) {
      char* d = (char*)(sB + s2 * 8192);
      stage_round(B, ldb, n0, k2, d, t);
      stage_round(B, ldb, n0 + 128, k2, d + 8192, t);
    }
    PHASE_SYNC_PRE();
#pragma unroll
    for (int m = 0; m < 4; ++m)
#pragma unroll
      for (int n = 0; n < 4; ++n)
        acc[4 + m][n] = __builtin_amdgcn_mfma_f32_16x16x32_bf16(
            af[m], bfr[n], acc[4 + m][n], 0, 0, 0);
    PHASE_SYNC_POST();
    if (tt + 2 < NT)
      asm volatile("s_waitcnt vmcnt(4)" ::: "memory");
    else if (tt + 1 < NT)
      asm volatile("s_waitcnt vmcnt(0)" ::: "memory");
    __builtin_amdgcn_s_barrier();
    cur = (cur == 2) ? 0 : cur + 1;
    s2 = (s2 == 2) ? 0 : s2 + 1;
  }

  // C/D layout: col = lane&15, row = (lane>>4)*4 + reg
  float* outz = outf + zstride * blockIdx.z;
#pragma unroll
  for (int m = 0; m < 8; ++m)
#pragma unroll
    for (int n = 0; n < 4; ++n) {
      const int row0 = m0 + wr * 128 + m * 16 + l4 * 4;
      const int col = n0 + wc * 64 + n * 16 + l15;
#pragma unroll
      for (int r = 0; r < 4; ++r)
        outz[(size_t)(row0 + r) * ldof + col] = acc[m][n][r];
    }
}

// ---- fused GLU GEMM: B-tile = [128 gate rows; 128 up rows] (BN=128) ----
// waves wc 0,1 accumulate gate for cols n0..n0+127; wc 2,3 accumulate up
// for the same cols; f32 LDS exchange computes silu(g)*u at full precision.
__global__ __launch_bounds__(512, 2)
void gemm8_glu(const bf16* __restrict__ A, const bf16* __restrict__ Bg,
               const bf16* __restrict__ Bu, bf16* __restrict__ out) {
  __shared__ __align__(16) char smem[98304];
  bf16* sA = (bf16*)smem;
  bf16* sB = (bf16*)(smem + 49152);
  const int t = threadIdx.x;
  const int lane = t & 63;
  const int l15 = lane & 15, l4 = lane >> 4;
  const int wid = t >> 6;
  const int wr = wid >> 2, wc = wid & 3;

  const int nwg = gridDim.x * gridDim.y;  // 512
  const int bid = blockIdx.y * gridDim.x + blockIdx.x;
  const int swz = (bid & 7) * (nwg >> 3) + (bid >> 3);
  const int m0 = (swz / gridDim.x) * 256;
  const int n0 = (swz % gridDim.x) * 128;

  const f32x4 zero = {0.f, 0.f, 0.f, 0.f};
  f32x4 acc[8][4];
#pragma unroll
  for (int m = 0; m < 8; ++m)
#pragma unroll
    for (int n = 0; n < 4; ++n) acc[m][n] = zero;

  stage_round(A, H_DIM, m0, 0, (char*)sA, t);
  stage_round(A, H_DIM, m0 + 128, 0, (char*)sA + 8192, t);
  stage_round(Bg, H_DIM, n0, 0, (char*)sB, t);
  stage_round(Bu, H_DIM, n0, 0, (char*)sB + 8192, t);
  stage_round(A, H_DIM, m0, 32, (char*)sA + 16384, t);
  stage_round(A, H_DIM, m0 + 128, 32, (char*)sA + 16384 + 8192, t);
  stage_round(Bg, H_DIM, n0, 32, (char*)sB + 16384, t);
  stage_round(Bu, H_DIM, n0, 32, (char*)sB + 16384 + 8192, t);
  asm volatile("s_waitcnt vmcnt(4)" ::: "memory");
  __builtin_amdgcn_s_barrier();

  int cur = 0, s2 = 2;
  const int NT = H_DIM / 32;  // 64
  for (int tt = 0; tt < NT; ++tt) {
    const bf16* sAc = sA + cur * 8192;
    const bf16* sBc = sB + cur * 8192;
    const int k2 = (tt + 2) * 32;
    bf16x8 af[4], bfr[4];
#pragma unroll
    for (int n = 0; n < 4; ++n)
      bfr[n] = frag_ld(sBc, wc * 64 + n * 16 + l15, l4);
#pragma unroll
    for (int m = 0; m < 4; ++m)
      af[m] = frag_ld(sAc, wr * 128 + m * 16 + l15, l4);
    if (tt + 2 < NT) {
      char* d = (char*)(sA + s2 * 8192);
      stage_round(A, H_DIM, m0, k2, d, t);
      stage_round(A, H_DIM, m0 + 128, k2, d + 8192, t);
    }
    PHASE_SYNC_PRE();
#pragma unroll
    for (int m = 0; m < 4; ++m)
#pragma unroll
      for (int n = 0; n < 4; ++n)
        acc[m][n] = __builtin_amdgcn_mfma_f32_16x16x32_bf16(
            af[m], bfr[n], acc[m][n], 0, 0, 0);
    PHASE_SYNC_POST();
    __builtin_amdgcn_s_barrier();
#pragma unroll
    for (int m = 0; m < 4; ++m)
      af[m] = frag_ld(sAc, wr * 128 + 64 + m * 16 + l15, l4);
    if (tt + 2 < NT) {
      char* d = (char*)(sB + s2 * 8192);
      stage_round(Bg, H_DIM, n0, k2, d, t);
      stage_round(Bu, H_DIM, n0, k2, d + 8192, t);
    }
    PHASE_SYNC_PRE();
#pragma unroll
    for (int m = 0; m < 4; ++m)
#pragma unroll
      for (int n = 0; n < 4; ++n)
        acc[4 + m][n] = __builtin_amdgcn_mfma_f32_16x16x32_bf16(
            af[m], bfr[n], acc[4 + m][n], 0, 0, 0);
    PHASE_SYNC_POST();
    if (tt + 2 < NT)
      asm volatile("s_waitcnt vmcnt(4)" ::: "memory");
    else if (tt + 1 < NT)
      asm volatile("s_waitcnt vmcnt(0)" ::: "memory");
    __builtin_amdgcn_s_barrier();
    cur = (cur == 2) ? 0 : cur + 1;
    s2 = (s2 == 2) ? 0 : s2 + 1;
  }

  // epilogue: up waves (wc>=2) push f32 acc through LDS; gate waves fuse.
  float* upf = (float*)smem;              // 128 x 129 f32 = 66048 B
  const int isUp = (wc >= 2);
  const int colL = (isUp ? (wc - 2) : wc) * 64;
#pragma unroll
  for (int c = 0; c < 2; ++c) {
    __syncthreads();
    if (isUp) {
#pragma unroll
      for (int m = 0; m < 4; ++m)
#pragma unroll
        for (int n = 0; n < 4; ++n)
#pragma unroll
          for (int r = 0; r < 4; ++r)
            upf[(wr * 64 + m * 16 + l4 * 4 + r) * 129 + colL + n * 16 + l15] =
                acc[c * 4 + m][n][r];
    }
    __syncthreads();
    if (!isUp) {
#pragma unroll
      for (int m = 0; m < 4; ++m)
#pragma unroll
        for (int n = 0; n < 4; ++n)
#pragma unroll
          for (int r = 0; r < 4; ++r) {
            const float g = acc[c * 4 + m][n][r];
            const float u = upf[(wr * 64 + m * 16 + l4 * 4 + r) * 129 + colL +
                                n * 16 + l15];
            const float sg = g / (1.f + __expf(-g));
            out[(size_t)(m0 + wr * 128 + c * 64 + m * 16 + l4 * 4 + r) *
                    INTER_DIM +
                n0 + colL + n * 16 + l15] = (bf16)(sg * u);
          }
    }
  }
}

// ---------------- GEMM: C[M,N] = A[M,K](bf16) @ B[N,K](bf16)^T -------------
// (m97-structure 128x128 kernel, kept for the O projection)
__global__ __launch_bounds__(256, 3)
void gemm_bt(const bf16* __restrict__ A, int lda,
             const bf16* __restrict__ B, int ldb, int kpb,
             float* __restrict__ outf, int ldof, size_t zstride) {
  __shared__ bf16 sA[2 * 128 * 32];
  __shared__ bf16 sB[2 * 128 * 32];
  const int t = threadIdx.x;
  const int lane = t & 63;
  const int l15 = lane & 15, l4 = lane >> 4;
  const int wm = ((t >> 6) >> 1) * 64;
  const int wn = ((t >> 6) & 1) * 64;
  const int m0 = blockIdx.y * 128;
  const int n0 = blockIdx.x * 128;
  const int kbeg = blockIdx.z * kpb;
  const int kend = kbeg + kpb;

  const f32x4 zero = {0.f, 0.f, 0.f, 0.f};
  f32x4 acc[4][4];
#pragma unroll
  for (int i = 0; i < 4; ++i)
#pragma unroll
    for (int j = 0; j < 4; ++j) acc[i][j] = zero;

  for (int k0 = kbeg; k0 < kend; k0 += 64) {
#pragma unroll
    for (int i = 0; i < 4; ++i) {
      const int flat = i * 4096 + t * 16;
      const int kc = flat >> 13;
      const int wb = flat & 8191;
      const int r = wb >> 6, ce = (wb & 63) >> 1;
      const int gc = k0 + kc * 32 + ce;
      load_lds16(A + (size_t)(m0 + r) * lda + gc, (char*)sA + flat);
      load_lds16(B + (size_t)(n0 + r) * ldb + gc, (char*)sB + flat);
    }
    __syncthreads();

#pragma unroll
    for (int kc = 0; kc < 2; ++kc) {
      bf16x8 af[4], bfr[4];
#pragma unroll
      for (int mi = 0; mi < 4; ++mi)
        af[mi] = *(const bf16x8*)(&sA[kc * 4096 + (wm + mi * 16 + l15) * 32 +
                                      l4 * 8]);
#pragma unroll
      for (int ni = 0; ni < 4; ++ni)
        bfr[ni] = *(const bf16x8*)(&sB[kc * 4096 + (wn + ni * 16 + l15) * 32 +
                                       l4 * 8]);
#pragma unroll
      for (int mi = 0; mi < 4; ++mi)
#pragma unroll
        for (int ni = 0; ni < 4; ++ni)
          acc[mi][ni] = __builtin_amdgcn_mfma_f32_16x16x32_bf16(
              af[mi], bfr[ni], acc[mi][ni], 0, 0, 0);
    }
    __syncthreads();
  }

#pragma unroll
  for (int mi = 0; mi < 4; ++mi) {
#pragma unroll
    for (int ni = 0; ni < 4; ++ni) {
      const int row0 = m0 + wm + mi * 16 + l4 * 4;
      const int col = n0 + wn + ni * 16 + l15;
#pragma unroll
      for (int r = 0; r < 4; ++r)
        outf[zstride * blockIdx.z + (size_t)(row0 + r) * ldof + col] =
            acc[mi][ni][r];
    }
  }
}

// ---------------- Flash attention, segment-causal ----------------
__global__ __launch_bounds__(256, 2)
void attn_fwd(const bf16* __restrict__ qkv, const int* __restrict__ cu,
              bf16* __restrict__ out) {
  const int h = blockIdx.y;
  const int q0 = blockIdx.x * 64;
  const int kvh = h >> 2;
  const int t = threadIdx.x;
  const int lane = t & 63;
  const int w = t >> 6;
  const int l15 = lane & 15, l4 = lane >> 4;

  __shared__ bf16 sK[64 * 136];
  __shared__ bf16 sVt[128 * 72];
  __shared__ bf16 sP[4][16 * 64];

  const int c1 = cu[1], c2 = cu[2];
  const int seg0 = (q0 >= c2) ? c2 : ((q0 >= c1) ? c1 : 0);

  const int qrow = q0 + w * 16 + l15;
  bf16x8 qf[4];
#pragma unroll
  for (int kc = 0; kc < 4; ++kc) {
    bf16x8 v = *(const bf16x8*)(qkv + (size_t)qrow * QKV_LD + h * 128 +
                                kc * 32 + l4 * 8);
#pragma unroll
    for (int j = 0; j < 8; ++j)
      v[j] = (bf16)((float)v[j] * 0.08838834764831845f);
    qf[kc] = v;
  }

  const f32x4 zero = {0.f, 0.f, 0.f, 0.f};
  f32x4 oacc[8];
#pragma unroll
  for (int i = 0; i < 8; ++i) oacc[i] = zero;
  float mi[4] = {-1e30f, -1e30f, -1e30f, -1e30f};
  float li[4] = {0.f, 0.f, 0.f, 0.f};

  for (int k0 = seg0; k0 <= q0; k0 += 64) {
#pragma unroll
    for (int it = 0; it < 4; ++it) {
      const int flat = it * 4096 + t * 16;
      const int r = flat >> 8, db = flat & 255;
      *(bf16x8*)((char*)sK + r * 272 + db) = *(const bf16x8*)(
          (const char*)(qkv + (size_t)(k0 + r) * QKV_LD + 2048 + kvh * 128) +
          db);
      const int chunk = it * 256 + t;
      const int vr = chunk & 63, dc = chunk >> 6;
      bf16x8 vv = *(const bf16x8*)(qkv + (size_t)(k0 + vr) * QKV_LD + 2560 +
                                   kvh * 128 + dc * 8);
#pragma unroll
      for (int j = 0; j < 8; ++j) sVt[(dc * 8 + j) * 72 + vr] = vv[j];
    }
    __syncthreads();

    f32x4 sacc[4];
#pragma unroll
    for (int kg = 0; kg < 4; ++kg) {
      f32x4 a = zero;
#pragma unroll
      for (int kc = 0; kc < 4; ++kc) {
        bf16x8 kf = *(const bf16x8*)((const char*)sK + (kg * 16 + l15) * 272 +
                                     kc * 64 + l4 * 16);
        a = __builtin_amdgcn_mfma_f32_16x16x32_bf16(qf[kc], kf, a, 0, 0, 0);
      }
      sacc[kg] = a;
    }

    if (k0 == q0) {
#pragma unroll
      for (int kg = 0; kg < 4; ++kg) {
        const int kk = kg * 16 + l15;
#pragma unroll
        for (int r = 0; r < 4; ++r) {
          const int qq = w * 16 + l4 * 4 + r;
          if (kk > qq) sacc[kg][r] = -1e30f;
        }
      }
    }

    float mx[4], al[4], rs[4];
#pragma unroll
    for (int r = 0; r < 4; ++r)
      mx[r] = fmaxf(fmaxf(sacc[0][r], sacc[1][r]),
                    fmaxf(sacc[2][r], sacc[3][r]));
#pragma unroll
    for (int off = 1; off < 16; off <<= 1)
#pragma unroll
      for (int r = 0; r < 4; ++r)
        mx[r] = fmaxf(mx[r], __shfl_xor(mx[r], off, 64));
#pragma unroll
    for (int r = 0; r < 4; ++r) {
      const float mn = fmaxf(mi[r], mx[r]);
      al[r] = __expf(mi[r] - mn);
      mi[r] = mn;
      rs[r] = 0.f;
    }
#pragma unroll
    for (int kg = 0; kg < 4; ++kg)
#pragma unroll
      for (int r = 0; r < 4; ++r) {
        const float p = __expf(sacc[kg][r] - mi[r]);
        sacc[kg][r] = p;
        rs[r] += p;
      }
#pragma unroll
    for (int off = 1; off < 16; off <<= 1)
#pragma unroll
      for (int r = 0; r < 4; ++r) rs[r] += __shfl_xor(rs[r], off, 64);
#pragma unroll
    for (int r = 0; r < 4; ++r) li[r] = li[r] * al[r] + rs[r];
#pragma unroll
    for (int dn = 0; dn < 8; ++dn)
#pragma unroll
      for (int r = 0; r < 4; ++r) oacc[dn][r] *= al[r];

#pragma unroll
    for (int kg = 0; kg < 4; ++kg)
#pragma unroll
      for (int r = 0; r < 4; ++r)
        sP[w][(l4 * 4 + r) * 64 + kg * 16 + l15] = (bf16)sacc[kg][r];

    bf16x8 pf[2];
#pragma unroll
    for (int kc2 = 0; kc2 < 2; ++kc2)
      pf[kc2] = *(const bf16x8*)(&sP[w][l15 * 64 + kc2 * 32 + l4 * 8]);
#pragma unroll
    for (int dn = 0; dn < 8; ++dn)
#pragma unroll
      for (int kc2 = 0; kc2 < 2; ++kc2) {
        bf16x8 vf = *(const bf16x8*)(&sVt[(dn * 16 + l15) * 72 + kc2 * 32 +
                                          l4 * 8]);
        oacc[dn] = __builtin_amdgcn_mfma_f32_16x16x32_bf16(pf[kc2], vf,
                                                           oacc[dn], 0, 0, 0);
      }
    __syncthreads();
  }

#pragma unroll
  for (int dn = 0; dn < 8; ++dn)
#pragma unroll
    for (int r = 0; r < 4; ++r) {
      const size_t m = (size_t)(q0 + w * 16 + l4 * 4 + r);
      out[m * H_DIM + h * 128 + dn * 16 + l15] = (bf16)(oacc[dn][r] / li[r]);
    }
}

// ---------------- Host launcher ----------------
extern "C" void kernel_launch(void* const* d_in, const int* in_sizes, int n_in,
                              void* d_out, int out_size, void* d_ws,
                              size_t ws_size, hipStream_t stream) {
  (void)in_sizes; (void)n_in; (void)out_size; (void)ws_size;
  const float* hs     = (const float*)d_in[0];
  const int*   cu     = (const int*)d_in[1];
  const float* ln1    = (const float*)d_in[2];
  const float* ln2    = (const float*)d_in[3];
  const float* q_w    = (const float*)d_in[4];
  const float* k_w    = (const float*)d_in[5];
  const float* v_w    = (const float*)d_in[6];
  const float* o_w    = (const float*)d_in[7];
  const float* gate_w = (const float*)d_in[8];
  const float* up_w   = (const float*)d_in[9];
  const float* down_w = (const float*)d_in[10];

  float* out_hidden = (float*)d_out;
  float* out_k = out_hidden + (size_t)L_SEQ * H_DIM;
  float* out_v = out_k + (size_t)L_SEQ * KV_DIM;

  char* ws = (char*)d_ws;
  bf16* WB = (bf16*)ws;
  const size_t wq_off = 0;
  const size_t wo_off = 6291456;
  const size_t wg_off = 10485760;
  const size_t wu_off = 27262976;
  const size_t wd_off = 44040192;

  bf16*  normed1 = (bf16*)(ws + ((size_t)116 << 20));
  bf16*  qkv     = (bf16*)(ws + ((size_t)124 << 20));
  bf16*  attnb   = (bf16*)(ws + ((size_t)136 << 20));
  bf16*  normed2 = (bf16*)(ws + ((size_t)144 << 20));
  bf16*  interb  = (bf16*)(ws + ((size_t)152 << 20));
  float* qpart   = (float*)(ws + ((size_t)136 << 20));
  float* opart   = (float*)(ws + ((size_t)152 << 20));
  float* dpart   = (float*)(ws);

  dim3 blk(256);

  // 0) convert all weights to bf16
  cvt_all<<<29696, blk, 0, stream>>>(q_w, k_w, v_w, o_w, gate_w, up_w, down_w,
                                     WB);

  // 1) normed1 = rmsnorm(hidden_states)
  rmsnorm_bf16<<<L_SEQ, blk, 0, stream>>>(hs, ln1, normed1);

  // 2) QKV projection (8-phase engine), split-K=2 -> fp32 partials; combine
  gemm8_bt<<<dim3(12, 8, 2), dim3(512), 0, stream>>>(
      normed1, H_DIM, WB + wq_off, H_DIM, 1024, qpart, QKV_LD,
      (size_t)L_SEQ * QKV_LD);
  qkv_combine<<<6144, blk, 0, stream>>>(qpart, (size_t)L_SEQ * QKV_LD, qkv,
                                        out_k, out_v);

  // 3) attention
  attn_fwd<<<dim3(32, 16), blk, 0, stream>>>(qkv, cu, attnb);

  // 4) O projection (m97 kernel), split-K=2 -> partials
  gemm_bt<<<dim3(16, 16, 2), blk, 0, stream>>>(
      attnb, H_DIM, WB + wo_off, H_DIM, 1024, opart, H_DIM,
      (size_t)L_SEQ * H_DIM);

  // 5) hidden = opart0+opart1+hs ; normed2 = rmsnorm(hidden)
  add_rmsnorm<<<L_SEQ, blk, 0, stream>>>(opart, opart + (size_t)L_SEQ * H_DIM,
                                         hs, ln2, out_hidden, normed2);

  // 6) inter = silu(normed2 @ gate^T) * (normed2 @ up^T)  (fused, 8-phase)
  gemm8_glu<<<dim3(64, 8), dim3(512), 0, stream>>>(normed2, WB + wg_off,
                                                   WB + wu_off, interb);

  // 7) down projection (8-phase engine), split-K=4 -> partials
  gemm8_bt<<<dim3(8, 8, 4), dim3(512), 0, stream>>>(
      interb, INTER_DIM, WB + wd_off, INTER_DIM, 2048, dpart, H_DIM,
      (size_t)L_SEQ * H_DIM);

  // 8) out = sum(dpart[0..3]) + hidden
  reduce_add4<<<4096, blk, 0, stream>>>(dpart, (size_t)L_SEQ * H_DIM,
                                        out_hidden, out_hidden);
}

// Round 2
// 576.453 us; speedup vs baseline: 1.1328x; 1.0829x over previous
//
#include <hip/hip_runtime.h>
#include <stdint.h>

typedef __bf16 bf16;
typedef __bf16 bf16x8 __attribute__((ext_vector_type(8)));
typedef __bf16 bf16x4v __attribute__((ext_vector_type(4)));
typedef float f32x4 __attribute__((ext_vector_type(4)));

#define L_SEQ 2048
#define H_DIM 2048
#define KV_DIM 512
#define QKV_LD 3072
#define INTER_DIM 8192

__device__ __forceinline__ void load_lds16(const void* g, void* l) {
  __builtin_amdgcn_global_load_lds(
      (const __attribute__((address_space(1))) void*)g,
      (__attribute__((address_space(3))) void*)l, 16, 0, 0);
}

// ---------------- fused fp32 -> bf16 convert of all 7 weights -------------
__global__ __launch_bounds__(256)
void cvt_all(const float* __restrict__ q, const float* __restrict__ k,
             const float* __restrict__ v, const float* __restrict__ o,
             const float* __restrict__ g, const float* __restrict__ u,
             const float* __restrict__ dn, bf16* __restrict__ WB) {
  const int b = blockIdx.x;
  const float* s;
  size_t doff;
  int lb;
  if (b < 2048)       { s = q;  doff = 0;        lb = b; }
  else if (b < 2560)  { s = k;  doff = 4194304;  lb = b - 2048; }
  else if (b < 3072)  { s = v;  doff = 5242880;  lb = b - 2560; }
  else if (b < 5120)  { s = o;  doff = 6291456;  lb = b - 3072; }
  else if (b < 13312) { s = g;  doff = 10485760; lb = b - 5120; }
  else if (b < 21504) { s = u;  doff = 27262976; lb = b - 13312; }
  else                { s = dn; doff = 44040192; lb = b - 21504; }
  const size_t i = (size_t)lb * 2048 + threadIdx.x * 8;
  float4 a = *(const float4*)(s + i);
  float4 c = *(const float4*)(s + i + 4);
  bf16x8 ov;
  ov[0] = (bf16)a.x; ov[1] = (bf16)a.y; ov[2] = (bf16)a.z; ov[3] = (bf16)a.w;
  ov[4] = (bf16)c.x; ov[5] = (bf16)c.y; ov[6] = (bf16)c.z; ov[7] = (bf16)c.w;
  *(bf16x8*)(WB + doff + i) = ov;
}

// ---------------- RMSNorm: fp32 in -> bf16 out ----------------
__global__ __launch_bounds__(256)
void rmsnorm_bf16(const float* __restrict__ x, const float* __restrict__ w,
                  bf16* __restrict__ out) {
  const int row = blockIdx.x;
  const int t = threadIdx.x;
  const float* xr = x + (size_t)row * H_DIM + t * 8;
  float4 a = *(const float4*)xr;
  float4 b = *(const float4*)(xr + 4);
  float ss = a.x * a.x + a.y * a.y + a.z * a.z + a.w * a.w +
             b.x * b.x + b.y * b.y + b.z * b.z + b.w * b.w;
#pragma unroll
  for (int off = 1; off < 64; off <<= 1) ss += __shfl_xor(ss, off, 64);
  __shared__ float red[4];
  if ((t & 63) == 0) red[t >> 6] = ss;
  __syncthreads();
  ss = red[0] + red[1] + red[2] + red[3];
  const float rs = rsqrtf(ss * (1.0f / H_DIM) + 1e-6f);
  float4 w1 = *(const float4*)(w + t * 8);
  float4 w2 = *(const float4*)(w + t * 8 + 4);
  bf16x8 o;
  o[0] = (bf16)(a.x * rs * w1.x);
  o[1] = (bf16)(a.y * rs * w1.y);
  o[2] = (bf16)(a.z * rs * w1.z);
  o[3] = (bf16)(a.w * rs * w1.w);
  o[4] = (bf16)(b.x * rs * w2.x);
  o[5] = (bf16)(b.y * rs * w2.y);
  o[6] = (bf16)(b.z * rs * w2.z);
  o[7] = (bf16)(b.w * rs * w2.w);
  *(bf16x8*)(out + (size_t)row * H_DIM + t * 8) = o;
}

// -------- fused: hidden = p0+p1+res ; normed = rmsnorm(hidden) --------
__global__ __launch_bounds__(256)
void add_rmsnorm(const float* __restrict__ p0, const float* __restrict__ p1,
                 const float* __restrict__ res, const float* __restrict__ w,
                 float* __restrict__ hidden, bf16* __restrict__ normed) {
  const int row = blockIdx.x;
  const int t = threadIdx.x;
  const size_t base = (size_t)row * H_DIM + t * 8;
  float4 a0 = *(const float4*)(p0 + base);
  float4 a1 = *(const float4*)(p0 + base + 4);
  float4 b0 = *(const float4*)(p1 + base);
  float4 b1 = *(const float4*)(p1 + base + 4);
  float4 c0 = *(const float4*)(res + base);
  float4 c1 = *(const float4*)(res + base + 4);
  float4 h0, h1;
  h0.x = a0.x + b0.x + c0.x; h0.y = a0.y + b0.y + c0.y;
  h0.z = a0.z + b0.z + c0.z; h0.w = a0.w + b0.w + c0.w;
  h1.x = a1.x + b1.x + c1.x; h1.y = a1.y + b1.y + c1.y;
  h1.z = a1.z + b1.z + c1.z; h1.w = a1.w + b1.w + c1.w;
  *(float4*)(hidden + base) = h0;
  *(float4*)(hidden + base + 4) = h1;
  float ss = h0.x * h0.x + h0.y * h0.y + h0.z * h0.z + h0.w * h0.w +
             h1.x * h1.x + h1.y * h1.y + h1.z * h1.z + h1.w * h1.w;
#pragma unroll
  for (int off = 1; off < 64; off <<= 1) ss += __shfl_xor(ss, off, 64);
  __shared__ float red[4];
  if ((t & 63) == 0) red[t >> 6] = ss;
  __syncthreads();
  ss = red[0] + red[1] + red[2] + red[3];
  const float rs = rsqrtf(ss * (1.0f / H_DIM) + 1e-6f);
  float4 w1 = *(const float4*)(w + t * 8);
  float4 w2 = *(const float4*)(w + t * 8 + 4);
  bf16x8 o;
  o[0] = (bf16)(h0.x * rs * w1.x);
  o[1] = (bf16)(h0.y * rs * w1.y);
  o[2] = (bf16)(h0.z * rs * w1.z);
  o[3] = (bf16)(h0.w * rs * w1.w);
  o[4] = (bf16)(h1.x * rs * w2.x);
  o[5] = (bf16)(h1.y * rs * w2.y);
  o[6] = (bf16)(h1.z * rs * w2.z);
  o[7] = (bf16)(h1.w * rs * w2.w);
  *(bf16x8*)(normed + (size_t)row * H_DIM + t * 8) = o;
}

// ---------------- out = p0+p1+p2+p3 + res (float4) ----------------
__global__ __launch_bounds__(256)
void reduce_add4(const float* __restrict__ p, size_t zs,
                 const float* __restrict__ res, float* __restrict__ out) {
  const size_t i = ((size_t)blockIdx.x * 256 + threadIdx.x) * 4;
  float4 a = *(const float4*)(p + i);
  float4 b = *(const float4*)(p + zs + i);
  float4 c = *(const float4*)(p + 2 * zs + i);
  float4 d = *(const float4*)(p + 3 * zs + i);
  float4 r = *(const float4*)(res + i);
  float4 o;
  o.x = a.x + b.x + c.x + d.x + r.x;
  o.y = a.y + b.y + c.y + d.y + r.y;
  o.z = a.z + b.z + c.z + d.z + r.z;
  o.w = a.w + b.w + c.w + d.w + r.w;
  *(float4*)(out + i) = o;
}

// ------- qkv combine: sum 2 fp32 partials -> bf16 qkv + fp32 K/V out ------
__global__ __launch_bounds__(256)
void qkv_combine(const float* __restrict__ p, size_t zs,
                 bf16* __restrict__ qkv, float* __restrict__ outk,
                 float* __restrict__ outv) {
  const size_t i = ((size_t)blockIdx.x * 256 + threadIdx.x) * 4;
  float4 a = *(const float4*)(p + i);
  float4 b = *(const float4*)(p + zs + i);
  float4 s;
  s.x = a.x + b.x; s.y = a.y + b.y; s.z = a.z + b.z; s.w = a.w + b.w;
  bf16x4v o;
  o[0] = (bf16)s.x; o[1] = (bf16)s.y; o[2] = (bf16)s.z; o[3] = (bf16)s.w;
  *(bf16x4v*)(qkv + i) = o;
  const int col = (int)(i % QKV_LD);
  const size_t row = i / QKV_LD;
  if (col >= 2560)      *(float4*)(outv + row * KV_DIM + (col - 2560)) = s;
  else if (col >= 2048) *(float4*)(outk + row * KV_DIM + (col - 2048)) = s;
}

// ================== 256x256 BK=64 quadrant-phase GEMM engine ==============
// 512 thr = 8 waves (2M x 4N); per-wave out 128x64 (acc 32 f32x4).
// LDS: 2 buffers x (A 32KB + B 32KB) = 128 KiB; halves of 128 rows x 64 k.
// Swizzle: 16B slot s at row r holds global k-slot s^(r&7); linear LDS dest
// (global source pre-swizzled), ds_read applies same XOR -> 8 lanes/quad.
// Phases per K-tile: (mh0,nh0),(mh0,nh1),(mh1,nh0),(mh1,nh1); phase p
// reads one A-half/B-half; A cached across nh, B cached across mh.
// Staging: halves of tile t+1 in first-use order [A0,B0,B1,A1], one per
// phase of tile t; waits vmcnt(4) at p0/p1/p2 (last tile: 4/2/0) -> loads
// always >=3 phases of lead, never drained in steady state.

#define LOAD_A(halfp)                                                      \
  _Pragma("unroll") for (int mi = 0; mi < 4; ++mi)                         \
      _Pragma("unroll") for (int kc = 0; kc < 2; ++kc)                     \
          af[mi][kc] = *(const bf16x8*)((halfp) + aoff[mi][kc]);

#define LOAD_B(nh, halfp)                                                  \
  _Pragma("unroll") for (int ni = 0; ni < 2; ++ni)                         \
      _Pragma("unroll") for (int kc = 0; kc < 2; ++kc)                     \
          bfv[nh][ni][kc] = *(const bf16x8*)((halfp) + boff[ni][kc]);

#define MFMA_QUAD(mh, nh)                                                  \
  _Pragma("unroll") for (int mi = 0; mi < 4; ++mi)                         \
      _Pragma("unroll") for (int ni = 0; ni < 2; ++ni)                     \
          _Pragma("unroll") for (int kc = 0; kc < 2; ++kc)                 \
              acc[mh][nh][mi][ni] = __builtin_amdgcn_mfma_f32_16x16x32_bf16( \
                  af[mi][kc], bfv[nh][ni][kc], acc[mh][nh][mi][ni], 0, 0, 0);

#define WAIT_LGKM0()                                      \
  asm volatile("s_waitcnt lgkmcnt(0)" ::: "memory");      \
  __builtin_amdgcn_sched_barrier(0)

#define WAIT_VM(n)                                        \
  asm volatile("s_waitcnt vmcnt(" #n ")" ::: "memory");   \
  __builtin_amdgcn_sched_barrier(0)

// ---- split-K B^T GEMM: C[M,N] = A[M,K] @ B[N,K]^T, fp32 partials ----
__global__ __launch_bounds__(512, 2)
void gemm8_bt(const bf16* __restrict__ A, int lda,
              const bf16* __restrict__ B, int ldb, int kpb,
              float* __restrict__ outf, int ldof, size_t zstride) {
  __shared__ __align__(16) bf16 smem[65536];  // 128 KiB
  bf16* sA = smem;          // 2 x 16384 elems
  bf16* sB = smem + 32768;
  char* smb = (char*)smem;  // byte view: A bufs @0,32768; B @65536,98304
  const int t = threadIdx.x;
  const int lane = t & 63;
  const int l15 = lane & 15, l4 = lane >> 4;
  const int wid = t >> 6;
  const int wr = wid >> 2, wc = wid & 3;

  // block mapping: partition N across XCDs when gn % 8 == 0
  const int gn = gridDim.x, gm = gridDim.y;
  const int bid = blockIdx.y * gn + blockIdx.x;
  int mb, nb;
  if ((gn & 7) == 0) {
    const int j = bid & 7, local = bid >> 3, npx = gn >> 3;
    nb = j * npx + local % npx;
    mb = local / npx;
  } else {
    nb = bid % gn;
    mb = bid / gn;
  }
  const int m0 = mb * 256, n0 = nb * 256;
  const int kbeg = blockIdx.z * kpb;
  const int NT = kpb >> 6;

  // per-lane frag element offsets within a 128x64 half
  int aoff[4][2], boff[2][2];
#pragma unroll
  for (int mi = 0; mi < 4; ++mi)
#pragma unroll
    for (int kc = 0; kc < 2; ++kc)
      aoff[mi][kc] = (wr * 64 + mi * 16 + l15) * 64 +
                     ((((kc << 2) | l4) ^ (l15 & 7)) << 3);
#pragma unroll
  for (int ni = 0; ni < 2; ++ni)
#pragma unroll
    for (int kc = 0; kc < 2; ++kc)
      boff[ni][kc] = (wc * 32 + ni * 16 + l15) * 64 +
                     ((((kc << 2) | l4) ^ (l15 & 7)) << 3);

  // staging source (per-thread): row rr, pre-swizzled k-slot
  const int rr = t >> 3;
  const int gs8 = (((t & 7) ^ (rr & 7)) << 3);
  const bf16* pa = A + (size_t)(m0 + rr) * lda + gs8;
  const bf16* pb = B + (size_t)(n0 + rr) * ldb + gs8;
  const size_t la = (size_t)64 * lda, lb = (size_t)64 * ldb;
  const int dln = t * 16;  // linear LDS byte offset within an 8KB chunk

  // prologue: tile 0 -> buf 0, issue order [A0, B0, B1, A1]
  {
    const size_t ko = (size_t)kbeg;
    load_lds16(pa + ko,          smb + dln);
    load_lds16(pa + ko + la,     smb + 8192 + dln);
    load_lds16(pb + ko,          smb + 65536 + dln);
    load_lds16(pb + ko + lb,     smb + 65536 + 8192 + dln);
    load_lds16(pb + ko + 2 * lb, smb + 65536 + 16384 + dln);
    load_lds16(pb + ko + 3 * lb, smb + 65536 + 16384 + 8192 + dln);
    load_lds16(pa + ko + 2 * la, smb + 16384 + dln);
    load_lds16(pa + ko + 3 * la, smb + 16384 + 8192 + dln);
  }

  const f32x4 zero = {0.f, 0.f, 0.f, 0.f};
  f32x4 acc[2][2][4][2];
#pragma unroll
  for (int mh = 0; mh < 2; ++mh)
#pragma unroll
    for (int nh = 0; nh < 2; ++nh)
#pragma unroll
      for (int mi = 0; mi < 4; ++mi)
#pragma unroll
        for (int ni = 0; ni < 2; ++ni) acc[mh][nh][mi][ni] = zero;

  bf16x8 af[4][2], bfv[2][2][2];

  for (int tt = 0; tt < NT; ++tt) {
    const int cur = tt & 1, nxt = cur ^ 1;
    const bf16* A0p = sA + cur * 16384;
    const bf16* A1p = A0p + 8192;
    const bf16* B0p = sB + cur * 16384;
    const bf16* B1p = B0p + 8192;
    char* dA = smb + nxt * 32768;
    char* dB = smb + 65536 + nxt * 32768;
    const size_t ko = (size_t)kbeg + (size_t)(tt + 1) * 64;
    const bool st = (tt + 1 < NT);

    // ---- phase 0: quadrant (0,0); stage A0(t+1) ----
    WAIT_VM(4);
    __builtin_amdgcn_s_barrier();
    LOAD_A(A0p);
    LOAD_B(0, B0p);
    if (st) {
      load_lds16(pa + ko,      dA + dln);
      load_lds16(pa + ko + la, dA + 8192 + dln);
    }
    WAIT_LGKM0();
    __builtin_amdgcn_s_setprio(1);
    MFMA_QUAD(0, 0);
    __builtin_amdgcn_s_setprio(0);

    // ---- phase 1: quadrant (0,1); stage B0(t+1) ----
    if (st) { WAIT_VM(4); } else { WAIT_VM(2); }
    __builtin_amdgcn_s_barrier();
    LOAD_B(1, B1p);
    if (st) {
      load_lds16(pb + ko,      dB + dln);
      load_lds16(pb + ko + lb, dB + 8192 + dln);
    }
    WAIT_LGKM0();
    __builtin_amdgcn_s_setprio(1);
    MFMA_QUAD(0, 1);
    __builtin_amdgcn_s_setprio(0);

    // ---- phase 2: quadrant (1,0); stage B1(t+1) ----
    if (st) { WAIT_VM(4); } else { WAIT_VM(0); }
    __builtin_amdgcn_s_barrier();
    LOAD_A(A1p);
    if (st) {
      load_lds16(pb + ko + 2 * lb, dB + 16384 + dln);
      load_lds16(pb + ko + 3 * lb, dB + 16384 + 8192 + dln);
    }
    WAIT_LGKM0();
    __builtin_amdgcn_s_setprio(1);
    MFMA_QUAD(1, 0);
    __builtin_amdgcn_s_setprio(0);

    // ---- phase 3: quadrant (1,1); stage A1(t+1) ----
    __builtin_amdgcn_s_barrier();
    if (st) {
      load_lds16(pa + ko + 2 * la, dA + 16384 + dln);
      load_lds16(pa + ko + 3 * la, dA + 16384 + 8192 + dln);
    }
    __builtin_amdgcn_s_setprio(1);
    MFMA_QUAD(1, 1);
    __builtin_amdgcn_s_setprio(0);
    __builtin_amdgcn_sched_barrier(0);
  }

  // C/D layout: col = lane&15, row = (lane>>4)*4 + reg
  float* outz = outf + zstride * blockIdx.z;
#pragma unroll
  for (int mh = 0; mh < 2; ++mh)
#pragma unroll
    for (int nh = 0; nh < 2; ++nh)
#pragma unroll
      for (int mi = 0; mi < 4; ++mi)
#pragma unroll
        for (int ni = 0; ni < 2; ++ni) {
          const int row0 = m0 + mh * 128 + wr * 64 + mi * 16 + l4 * 4;
          const int col = n0 + nh * 128 + wc * 32 + ni * 16 + l15;
#pragma unroll
          for (int r = 0; r < 4; ++r)
            outz[(size_t)(row0 + r) * ldof + col] = acc[mh][nh][mi][ni][r];
        }
}

// ---- fused GLU: B-half0 = gate rows, B-half1 = up rows (same 128 cols);
// acc[mh][0]=gate, acc[mh][1]=up -> in-register silu(g)*u epilogue.
__global__ __launch_bounds__(512, 2)
void gemm8_glu(const bf16* __restrict__ A, const bf16* __restrict__ Bg,
               const bf16* __restrict__ Bu, bf16* __restrict__ out) {
  __shared__ __align__(16) bf16 smem[65536];
  bf16* sA = smem;
  bf16* sB = smem + 32768;
  char* smb = (char*)smem;
  const int t = threadIdx.x;
  const int lane = t & 63;
  const int l15 = lane & 15, l4 = lane >> 4;
  const int wid = t >> 6;
  const int wr = wid >> 2, wc = wid & 3;

  const int gn = gridDim.x;  // 64
  const int bid = blockIdx.y * gn + blockIdx.x;
  const int j = bid & 7, local = bid >> 3, npx = gn >> 3;
  const int nb = j * npx + local % npx;
  const int mb = local / npx;
  const int m0 = mb * 256, n0 = nb * 128;
  const int NT = H_DIM / 64;  // 32

  int aoff[4][2], boff[2][2];
#pragma unroll
  for (int mi = 0; mi < 4; ++mi)
#pragma unroll
    for (int kc = 0; kc < 2; ++kc)
      aoff[mi][kc] = (wr * 64 + mi * 16 + l15) * 64 +
                     ((((kc << 2) | l4) ^ (l15 & 7)) << 3);
#pragma unroll
  for (int ni = 0; ni < 2; ++ni)
#pragma unroll
    for (int kc = 0; kc < 2; ++kc)
      boff[ni][kc] = (wc * 32 + ni * 16 + l15) * 64 +
                     ((((kc << 2) | l4) ^ (l15 & 7)) << 3);

  const int rr = t >> 3;
  const int gs8 = (((t & 7) ^ (rr & 7)) << 3);
  const bf16* pa = A + (size_t)(m0 + rr) * H_DIM + gs8;
  const bf16* pg = Bg + (size_t)(n0 + rr) * H_DIM + gs8;
  const bf16* pu = Bu + (size_t)(n0 + rr) * H_DIM + gs8;
  const size_t la = (size_t)64 * H_DIM;
  const int dln = t * 16;

  // prologue: tile 0 -> buf 0, order [A0, B0(gate), B1(up), A1]
  load_lds16(pa,          smb + dln);
  load_lds16(pa + la,     smb + 8192 + dln);
  load_lds16(pg,          smb + 65536 + dln);
  load_lds16(pg + la,     smb + 65536 + 8192 + dln);
  load_lds16(pu,          smb + 65536 + 16384 + dln);
  load_lds16(pu + la,     smb + 65536 + 16384 + 8192 + dln);
  load_lds16(pa + 2 * la, smb + 16384 + dln);
  load_lds16(pa + 3 * la, smb + 16384 + 8192 + dln);

  const f32x4 zero = {0.f, 0.f, 0.f, 0.f};
  f32x4 acc[2][2][4][2];
#pragma unroll
  for (int mh = 0; mh < 2; ++mh)
#pragma unroll
    for (int nh = 0; nh < 2; ++nh)
#pragma unroll
      for (int mi = 0; mi < 4; ++mi)
#pragma unroll
        for (int ni = 0; ni < 2; ++ni) acc[mh][nh][mi][ni] = zero;

  bf16x8 af[4][2], bfv[2][2][2];

  for (int tt = 0; tt < NT; ++tt) {
    const int cur = tt & 1, nxt = cur ^ 1;
    const bf16* A0p = sA + cur * 16384;
    const bf16* A1p = A0p + 8192;
    const bf16* B0p = sB + cur * 16384;
    const bf16* B1p = B0p + 8192;
    char* dA = smb + nxt * 32768;
    char* dB = smb + 65536 + nxt * 32768;
    const size_t ko = (size_t)(tt + 1) * 64;
    const bool st = (tt + 1 < NT);

    WAIT_VM(4);
    __builtin_amdgcn_s_barrier();
    LOAD_A(A0p);
    LOAD_B(0, B0p);
    if (st) {
      load_lds16(pa + ko,      dA + dln);
      load_lds16(pa + ko + la, dA + 8192 + dln);
    }
    WAIT_LGKM0();
    __builtin_amdgcn_s_setprio(1);
    MFMA_QUAD(0, 0);
    __builtin_amdgcn_s_setprio(0);

    if (st) { WAIT_VM(4); } else { WAIT_VM(2); }
    __builtin_amdgcn_s_barrier();
    LOAD_B(1, B1p);
    if (st) {
      load_lds16(pg + ko,      dB + dln);
      load_lds16(pg + ko + la, dB + 8192 + dln);
    }
    WAIT_LGKM0();
    __builtin_amdgcn_s_setprio(1);
    MFMA_QUAD(0, 1);
    __builtin_amdgcn_s_setprio(0);

    if (st) { WAIT_VM(4); } else { WAIT_VM(0); }
    __builtin_amdgcn_s_barrier();
    LOAD_A(A1p);
    if (st) {
      load_lds16(pu + ko,      dB + 16384 + dln);
      load_lds16(pu + ko + la, dB + 16384 + 8192 + dln);
    }
    WAIT_LGKM0();
    __builtin_amdgcn_s_setprio(1);
    MFMA_QUAD(1, 0);
    __builtin_amdgcn_s_setprio(0);

    __builtin_amdgcn_s_barrier();
    if (st) {
      load_lds16(pa + ko + 2 * la, dA + 16384 + dln);
      load_lds16(pa + ko + 3 * la, dA + 16384 + 8192 + dln);
    }
    __builtin_amdgcn_s_setprio(1);
    MFMA_QUAD(1, 1);
    __builtin_amdgcn_s_setprio(0);
    __builtin_amdgcn_sched_barrier(0);
  }

  // epilogue: in-register GLU fusion (gate = nh0, up = nh1, same cols)
#pragma unroll
  for (int mh = 0; mh < 2; ++mh)
#pragma unroll
    for (int mi = 0; mi < 4; ++mi)
#pragma unroll
      for (int ni = 0; ni < 2; ++ni) {
        const int row0 = m0 + mh * 128 + wr * 64 + mi * 16 + l4 * 4;
        const int col = n0 + wc * 32 + ni * 16 + l15;
#pragma unroll
        for (int r = 0; r < 4; ++r) {
          const float g = acc[mh][0][mi][ni][r];
          const float u = acc[mh][1][mi][ni][r];
          const float sg = g / (1.f + __expf(-g));
          out[(size_t)(row0 + r) * INTER_DIM + col] = (bf16)(sg * u);
        }
      }
}

// ---------------- GEMM: C[M,N] = A[M,K](bf16) @ B[N,K](bf16)^T -------------
// (m97-structure 128x128 kernel, kept for the O projection)
__global__ __launch_bounds__(256, 3)
void gemm_bt(const bf16* __restrict__ A, int lda,
             const bf16* __restrict__ B, int ldb, int kpb,
             float* __restrict__ outf, int ldof, size_t zstride) {
  __shared__ bf16 sA[2 * 128 * 32];
  __shared__ bf16 sB[2 * 128 * 32];
  const int t = threadIdx.x;
  const int lane = t & 63;
  const int l15 = lane & 15, l4 = lane >> 4;
  const int wm = ((t >> 6) >> 1) * 64;
  const int wn = ((t >> 6) & 1) * 64;
  const int m0 = blockIdx.y * 128;
  const int n0 = blockIdx.x * 128;
  const int kbeg = blockIdx.z * kpb;
  const int kend = kbeg + kpb;

  const f32x4 zero = {0.f, 0.f, 0.f, 0.f};
  f32x4 acc[4][4];
#pragma unroll
  for (int i = 0; i < 4; ++i)
#pragma unroll
    for (int j = 0; j < 4; ++j) acc[i][j] = zero;

  for (int k0 = kbeg; k0 < kend; k0 += 64) {
#pragma unroll
    for (int i = 0; i < 4; ++i) {
      const int flat = i * 4096 + t * 16;
      const int kc = flat >> 13;
      const int wb = flat & 8191;
      const int r = wb >> 6, ce = (wb & 63) >> 1;
      const int gc = k0 + kc * 32 + ce;
      load_lds16(A + (size_t)(m0 + r) * lda + gc, (char*)sA + flat);
      load_lds16(B + (size_t)(n0 + r) * ldb + gc, (char*)sB + flat);
    }
    __syncthreads();

#pragma unroll
    for (int kc = 0; kc < 2; ++kc) {
      bf16x8 af[4], bfr[4];
#pragma unroll
      for (int mi = 0; mi < 4; ++mi)
        af[mi] = *(const bf16x8*)(&sA[kc * 4096 + (wm + mi * 16 + l15) * 32 +
                                      l4 * 8]);
#pragma unroll
      for (int ni = 0; ni < 4; ++ni)
        bfr[ni] = *(const bf16x8*)(&sB[kc * 4096 + (wn + ni * 16 + l15) * 32 +
                                       l4 * 8]);
#pragma unroll
      for (int mi = 0; mi < 4; ++mi)
#pragma unroll
        for (int ni = 0; ni < 4; ++ni)
          acc[mi][ni] = __builtin_amdgcn_mfma_f32_16x16x32_bf16(
              af[mi], bfr[ni], acc[mi][ni], 0, 0, 0);
    }
    __syncthreads();
  }

#pragma unroll
  for (int mi = 0; mi < 4; ++mi) {
#pragma unroll
    for (int ni = 0; ni < 4; ++ni) {
      const int row0 = m0 + wm + mi * 16 + l4 * 4;
      const int col = n0 + wn + ni * 16 + l15;
#pragma unroll
      for (int r = 0; r < 4; ++r)
        outf[zstride * blockIdx.z + (size_t)(row0 + r) * ldof + col] =
            acc[mi][ni][r];
    }
  }
}

// ---------------- Flash attention, segment-causal ----------------
__global__ __launch_bounds__(256, 2)
void attn_fwd(const bf16* __restrict__ qkv, const int* __restrict__ cu,
              bf16* __restrict__ out) {
  const int h = blockIdx.y;
  const int q0 = blockIdx.x * 64;
  const int kvh = h >> 2;
  const int t = threadIdx.x;
  const int lane = t & 63;
  const int w = t >> 6;
  const int l15 = lane & 15, l4 = lane >> 4;

  __shared__ bf16 sK[64 * 136];
  __shared__ bf16 sVt[128 * 72];
  __shared__ bf16 sP[4][16 * 64];

  const int c1 = cu[1], c2 = cu[2];
  const int seg0 = (q0 >= c2) ? c2 : ((q0 >= c1) ? c1 : 0);

  const int qrow = q0 + w * 16 + l15;
  bf16x8 qf[4];
#pragma unroll
  for (int kc = 0; kc < 4; ++kc) {
    bf16x8 v = *(const bf16x8*)(qkv + (size_t)qrow * QKV_LD + h * 128 +
                                kc * 32 + l4 * 8);
#pragma unroll
    for (int j = 0; j < 8; ++j)
      v[j] = (bf16)((float)v[j] * 0.08838834764831845f);
    qf[kc] = v;
  }

  const f32x4 zero = {0.f, 0.f, 0.f, 0.f};
  f32x4 oacc[8];
#pragma unroll
  for (int i = 0; i < 8; ++i) oacc[i] = zero;
  float mi[4] = {-1e30f, -1e30f, -1e30f, -1e30f};
  float li[4] = {0.f, 0.f, 0.f, 0.f};

  for (int k0 = seg0; k0 <= q0; k0 += 64) {
#pragma unroll
    for (int it = 0; it < 4; ++it) {
      const int flat = it * 4096 + t * 16;
      const int r = flat >> 8, db = flat & 255;
      *(bf16x8*)((char*)sK + r * 272 + db) = *(const bf16x8*)(
          (const char*)(qkv + (size_t)(k0 + r) * QKV_LD + 2048 + kvh * 128) +
          db);
      const int chunk = it * 256 + t;
      const int vr = chunk & 63, dc = chunk >> 6;
      bf16x8 vv = *(const bf16x8*)(qkv + (size_t)(k0 + vr) * QKV_LD + 2560 +
                                   kvh * 128 + dc * 8);
#pragma unroll
      for (int j = 0; j < 8; ++j) sVt[(dc * 8 + j) * 72 + vr] = vv[j];
    }
    __syncthreads();

    f32x4 sacc[4];
#pragma unroll
    for (int kg = 0; kg < 4; ++kg) {
      f32x4 a = zero;
#pragma unroll
      for (int kc = 0; kc < 4; ++kc) {
        bf16x8 kf = *(const bf16x8*)((const char*)sK + (kg * 16 + l15) * 272 +
                                     kc * 64 + l4 * 16);
        a = __builtin_amdgcn_mfma_f32_16x16x32_bf16(qf[kc], kf, a, 0, 0, 0);
      }
      sacc[kg] = a;
    }

    if (k0 == q0) {
#pragma unroll
      for (int kg = 0; kg < 4; ++kg) {
        const int kk = kg * 16 + l15;
#pragma unroll
        for (int r = 0; r < 4; ++r) {
          const int qq = w * 16 + l4 * 4 + r;
          if (kk > qq) sacc[kg][r] = -1e30f;
        }
      }
    }

    float mx[4], al[4], rs[4];
#pragma unroll
    for (int r = 0; r < 4; ++r)
      mx[r] = fmaxf(fmaxf(sacc[0][r], sacc[1][r]),
                    fmaxf(sacc[2][r], sacc[3][r]));
#pragma unroll
    for (int off = 1; off < 16; off <<= 1)
#pragma unroll
      for (int r = 0; r < 4; ++r)
        mx[r] = fmaxf(mx[r], __shfl_xor(mx[r], off, 64));
#pragma unroll
    for (int r = 0; r < 4; ++r) {
      const float mn = fmaxf(mi[r], mx[r]);
      al[r] = __expf(mi[r] - mn);
      mi[r] = mn;
      rs[r] = 0.f;
    }
#pragma unroll
    for (int kg = 0; kg < 4; ++kg)
#pragma unroll
      for (int r = 0; r < 4; ++r) {
        const float p = __expf(sacc[kg][r] - mi[r]);
        sacc[kg][r] = p;
        rs[r] += p;
      }
#pragma unroll
    for (int off = 1; off < 16; off <<= 1)
#pragma unroll
      for (int r = 0; r < 4; ++r) rs[r] += __shfl_xor(rs[r], off, 64);
#pragma unroll
    for (int r = 0; r < 4; ++r) li[r] = li[r] * al[r] + rs[r];
#pragma unroll
    for (int dn = 0; dn < 8; ++dn)
#pragma unroll
      for (int r = 0; r < 4; ++r) oacc[dn][r] *= al[r];

#pragma unroll
    for (int kg = 0; kg < 4; ++kg)
#pragma unroll
      for (int r = 0; r < 4; ++r)
        sP[w][(l4 * 4 + r) * 64 + kg * 16 + l15] = (bf16)sacc[kg][r];

    bf16x8 pf[2];
#pragma unroll
    for (int kc2 = 0; kc2 < 2; ++kc2)
      pf[kc2] = *(const bf16x8*)(&sP[w][l15 * 64 + kc2 * 32 + l4 * 8]);
#pragma unroll
    for (int dn = 0; dn < 8; ++dn)
#pragma unroll
      for (int kc2 = 0; kc2 < 2; ++kc2) {
        bf16x8 vf = *(const bf16x8*)(&sVt[(dn * 16 + l15) * 72 + kc2 * 32 +
                                          l4 * 8]);
        oacc[dn] = __builtin_amdgcn_mfma_f32_16x16x32_bf16(pf[kc2], vf,
                                                           oacc[dn], 0, 0, 0);
      }
    __syncthreads();
  }

#pragma unroll
  for (int dn = 0; dn < 8; ++dn)
#pragma unroll
    for (int r = 0; r < 4; ++r) {
      const size_t m = (size_t)(q0 + w * 16 + l4 * 4 + r);
      out[m * H_DIM + h * 128 + dn * 16 + l15] = (bf16)(oacc[dn][r] / li[r]);
    }
}

// ---------------- Host launcher ----------------
extern "C" void kernel_launch(void* const* d_in, const int* in_sizes, int n_in,
                              void* d_out, int out_size, void* d_ws,
                              size_t ws_size, hipStream_t stream) {
  (void)in_sizes; (void)n_in; (void)out_size; (void)ws_size;
  const float* hs     = (const float*)d_in[0];
  const int*   cu     = (const int*)d_in[1];
  const float* ln1    = (const float*)d_in[2];
  const float* ln2    = (const float*)d_in[3];
  const float* q_w    = (const float*)d_in[4];
  const float* k_w    = (const float*)d_in[5];
  const float* v_w    = (const float*)d_in[6];
  const float* o_w    = (const float*)d_in[7];
  const float* gate_w = (const float*)d_in[8];
  const float* up_w   = (const float*)d_in[9];
  const float* down_w = (const float*)d_in[10];

  float* out_hidden = (float*)d_out;
  float* out_k = out_hidden + (size_t)L_SEQ * H_DIM;
  float* out_v = out_k + (size_t)L_SEQ * KV_DIM;

  char* ws = (char*)d_ws;
  bf16* WB = (bf16*)ws;
  const size_t wq_off = 0;
  const size_t wo_off = 6291456;
  const size_t wg_off = 10485760;
  const size_t wu_off = 27262976;
  const size_t wd_off = 44040192;

  bf16*  normed1 = (bf16*)(ws + ((size_t)116 << 20));
  bf16*  qkv     = (bf16*)(ws + ((size_t)124 << 20));
  bf16*  attnb   = (bf16*)(ws + ((size_t)136 << 20));
  bf16*  normed2 = (bf16*)(ws + ((size_t)144 << 20));
  bf16*  interb  = (bf16*)(ws + ((size_t)152 << 20));
  float* qpart   = (float*)(ws + ((size_t)136 << 20));
  float* opart   = (float*)(ws + ((size_t)152 << 20));
  float* dpart   = (float*)(ws);

  dim3 blk(256);

  // 0) convert all weights to bf16
  cvt_all<<<29696, blk, 0, stream>>>(q_w, k_w, v_w, o_w, gate_w, up_w, down_w,
                                     WB);

  // 1) normed1 = rmsnorm(hidden_states)
  rmsnorm_bf16<<<L_SEQ, blk, 0, stream>>>(hs, ln1, normed1);

  // 2) QKV projection (quadrant engine), split-K=2 -> partials; combine
  gemm8_bt<<<dim3(12, 8, 2), dim3(512), 0, stream>>>(
      normed1, H_DIM, WB + wq_off, H_DIM, 1024, qpart, QKV_LD,
      (size_t)L_SEQ * QKV_LD);
  qkv_combine<<<6144, blk, 0, stream>>>(qpart, (size_t)L_SEQ * QKV_LD, qkv,
                                        out_k, out_v);

  // 3) attention
  attn_fwd<<<dim3(32, 16), blk, 0, stream>>>(qkv, cu, attnb);

  // 4) O projection (m97 kernel), split-K=2 -> partials
  gemm_bt<<<dim3(16, 16, 2), blk, 0, stream>>>(
      attnb, H_DIM, WB + wo_off, H_DIM, 1024, opart, H_DIM,
      (size_t)L_SEQ * H_DIM);

  // 5) hidden = opart0+opart1+hs ; normed2 = rmsnorm(hidden)
  add_rmsnorm<<<L_SEQ, blk, 0, stream>>>(opart, opart + (size_t)L_SEQ * H_DIM,
                                         hs, ln2, out_hidden, normed2);

  // 6) inter = silu(normed2 @ gate^T) * (normed2 @ up^T)  (fused quadrant)
  gemm8_glu<<<dim3(64, 8), dim3(512), 0, stream>>>(normed2, WB + wg_off,
                                                   WB + wu_off, interb);

  // 7) down projection (quadrant engine), split-K=4 -> partials
  gemm8_bt<<<dim3(8, 8, 4), dim3(512), 0, stream>>>(
      interb, INTER_DIM, WB + wd_off, INTER_DIM, 2048, dpart, H_DIM,
      (size_t)L_SEQ * H_DIM);

  // 8) out = sum(dpart[0..3]) + hidden
  reduce_add4<<<4096, blk, 0, stream>>>(dpart, (size_t)L_SEQ * H_DIM,
                                        out_hidden, out_hidden);
}